// Round 11
// baseline (496.146 us; speedup 1.0000x reference)
//
#include <hip/hip_runtime.h>
#include <hip/hip_cooperative_groups.h>
#include <math.h>

namespace cg = cooperative_groups;

#define B_   2
#define S_   2048
#define H_   1024
#define NH_  16
#define NKV_ 4
#define HD_  64
#define R_   (NH_ / NKV_)   // 4 q-heads per kv-head
#define QKVW 1536           // qkv row width (q 0..1023 | k 1024..1279 | v 1280..1535)

typedef __attribute__((ext_vector_type(8))) short bf16x8;
typedef __attribute__((ext_vector_type(4))) float f32x4;

__device__ inline short f2bf(float f) {
    unsigned u = __float_as_uint(f);
    u += 0x7FFF + ((u >> 16) & 1);     // RNE to bf16
    return (short)(u >> 16);
}

__device__ inline float exp2fast(float x) {
#if __has_builtin(__builtin_amdgcn_exp2f)
    return __builtin_amdgcn_exp2f(x);
#else
    float r; asm volatile("v_exp_f32 %0, %1\n\ts_nop 1" : "=v"(r) : "v"(x)); return r;
#endif
}

__device__ inline unsigned cvt_pk_bf16(float lo, float hi) {
    unsigned r;
    asm("v_cvt_pk_bf16_f32 %0, %1, %2" : "=v"(r) : "v"(lo), "v"(hi));
    return r;
}

#define LOG2E 1.4426950408889634f

// async global->LDS, 16 B per lane (m97/m104 semantics).
__device__ inline void gload_lds16(const void* gptr, void* lptr) {
    __builtin_amdgcn_global_load_lds(
        (const __attribute__((address_space(1))) unsigned int*)gptr,
        (__attribute__((address_space(3))) unsigned int*)lptr,
        16, 0, 0);
}

// ---------------------------------------------------------------------------
// MEGA kernel: all four stages in ONE cooperative launch.
//   Evidence: non-attn time has been invariant at ~126us across every GEMM
//   structure AND after deleting a whole pass (R10) -> dominated by fixed
//   per-launch/serialization overhead of 4 dependent dispatches, not by
//   kernel content. Fusing to 1 launch with grid.sync() is the direct test.
//   Grid: 256 blocks x 512 threads (1/CU, co-resident — coop-legal).
//   Phase 0: weight transposes, grid-stride 640 64x64 tiles.
//   Phase 1: gemm1 768 64x128-tiles (exactly 3/block), 8 waves of 16x64,
//            2-phase dbuf, fused fp32->bf16 A-convert, RoPE/Vtg epilogue.
//   Phase 2: attention v17 VERBATIM (best measured 57.5us; v18 reverted).
//   Phase 3: gemm2 512 64x128-tiles (exactly 2/block).
//   LDS: 55.8 KB union across phases.
// ---------------------------------------------------------------------------
__global__ __launch_bounds__(512, 1) void mega(const float* __restrict__ x,
                                               const float* __restrict__ cosb,
                                               const float* __restrict__ sinb,
                                               const float* __restrict__ maskb,
                                               const float* __restrict__ Wq,
                                               const float* __restrict__ Wk,
                                               const float* __restrict__ Wv,
                                               const float* __restrict__ Wo,
                                               short* __restrict__ qkv,
                                               short* __restrict__ Wqkvt,
                                               short* __restrict__ Wot,
                                               short* __restrict__ Vtg,
                                               float* __restrict__ out) {
    cg::grid_group grid = cg::this_grid();

    __shared__ union {
        struct { short T[64][68]; } tc;                                   // 8.7 KB
        struct { short Ah[2][64 * 32]; short Bh[2][128 * 32]; } g;        // 24 KB
        struct { short Ks[2][64 * 72]; short Vt[2][64 * 72];
                 short Ps[8][16 * 72]; float mskS[2][64]; } at;           // 55.8 KB
    } sm;

    const int tid  = threadIdx.x;
    const int bid  = blockIdx.x;
    const int w    = tid >> 6;           // 0..7
    const int lane = tid & 63;
    const int ln   = lane & 15;
    const int qd   = lane >> 4;

    // ======================= Phase 0: weight transposes ====================
    {
        const int r  = tid >> 4;         // 0..31
        const int c4 = (tid & 15) * 4;
        for (int bx = bid; bx < 640; bx += 256) {
            const float* W; short* Wt; int N, idx;
            if (bx < 256)      { W = Wq; Wt = Wqkvt;               N = 1024; idx = bx; }
            else if (bx < 320) { W = Wk; Wt = Wqkvt + 1024 * 1024; N = 256;  idx = bx - 256; }
            else if (bx < 384) { W = Wv; Wt = Wqkvt + 1280 * 1024; N = 256;  idx = bx - 320; }
            else               { W = Wo; Wt = Wot;                 N = 1024; idx = bx - 384; }
            const int ntiles = N >> 6;
            const int n0 = (idx % ntiles) * 64;
            const int k0 = (idx / ntiles) * 64;

            __syncthreads();             // previous tile's T reads done
#pragma unroll
            for (int t = 0; t < 2; t++) {
                int row = t * 32 + r;    // k index
                float4 v = *(const float4*)&W[(size_t)(k0 + row) * N + n0 + c4];
                sm.tc.T[c4 + 0][row] = f2bf(v.x);
                sm.tc.T[c4 + 1][row] = f2bf(v.y);
                sm.tc.T[c4 + 2][row] = f2bf(v.z);
                sm.tc.T[c4 + 3][row] = f2bf(v.w);
            }
            __syncthreads();
#pragma unroll
            for (int t = 0; t < 2; t++) {
                int row = t * 32 + r;    // n index
                short4 o = *(short4*)&sm.tc.T[row][c4];
                *(short4*)&Wt[(size_t)(n0 + row) * 1024 + k0 + c4] = o;
            }
        }
    }
    grid.sync();

    // ======================= Phase 1: GEMM1 fused ==========================
    {
        const int wr = w >> 1;           // 0..3 (16-row group)
        const int wc = w & 1;            // 0..1 (64-col group)
        const int sr = lane >> 2, sk = (lane & 3) * 8;
        const int ar  = tid >> 3;        // 0..63 A-convert row
        const int ac4 = (tid & 7) * 4;   // 0..28

        for (int tile = bid; tile < 768; tile += 256) {
            const int row0 = (tile / 12) * 64;
            const int col0 = (tile % 12) * 128;

            f32x4 acc[4];
#pragma unroll
            for (int ni = 0; ni < 4; ni++) acc[ni] = (f32x4){0.f, 0.f, 0.f, 0.f};

            const float* xp = x + (size_t)(row0 + ar) * 1024 + ac4;
            const short* bp = Wqkvt + (size_t)(col0 + w * 16 + sr) * 1024 + sk;

            {   // prologue: tile 0 -> buf 0
                float4 a1 = *(const float4*)xp;
                short4 o = { f2bf(a1.x), f2bf(a1.y), f2bf(a1.z), f2bf(a1.w) };
                *(short4*)&sm.g.Ah[0][ar * 32 + ac4] = o;
            }
            gload_lds16(bp, &sm.g.Bh[0][(w * 16) * 32]);
            __syncthreads();

            for (int t = 0; t < 32; t++) {
                const int cur = t & 1, nxt = cur ^ 1;
                if (t + 1 < 32) {
                    const int k1 = (t + 1) * 32;
                    gload_lds16(bp + k1, &sm.g.Bh[nxt][(w * 16) * 32]);
                    float4 a1 = *(const float4*)(xp + k1);
                    short4 o = { f2bf(a1.x), f2bf(a1.y), f2bf(a1.z), f2bf(a1.w) };
                    *(short4*)&sm.g.Ah[nxt][ar * 32 + ac4] = o;
                }
                bf16x8 af = *(const bf16x8*)&sm.g.Ah[cur][(wr * 16 + ln) * 32 + qd * 8];
                bf16x8 bfr[4];
#pragma unroll
                for (int ni = 0; ni < 4; ni++)
                    bfr[ni] = *(const bf16x8*)&sm.g.Bh[cur][(wc * 64 + ni * 16 + ln) * 32 + qd * 8];
#pragma unroll
                for (int ni = 0; ni < 4; ni++)
                    acc[ni] = __builtin_amdgcn_mfma_f32_16x16x32_bf16(af, bfr[ni], acc[ni], 0, 0, 0);
                __syncthreads();
            }

            const int colw = col0 + wc * 64;
            if (colw < H_ + NKV_ * HD_) {
                // q/k: RoPE in fp32, store bf16
#pragma unroll
                for (int i = 0; i < 4; i++) {
                    const int row  = row0 + wr * 16 + qd * 4 + i;
                    const int spos = row & (S_ - 1);
                    const float* cp = cosb + (size_t)spos * HD_;
                    const float* sp = sinb + (size_t)spos * HD_;
                    float o0[4];
#pragma unroll
                    for (int ni = 0; ni < 2; ni++) {
                        const int d = ni * 16 + ln;
                        float x0 = acc[ni][i], x1 = acc[ni + 2][i];
                        o0[ni]     = x0 * cp[d]      - x1 * sp[d];
                        o0[ni + 2] = x1 * cp[d + 32] + x0 * sp[d + 32];
                    }
                    short* Cp = qkv + (size_t)row * QKVW + colw + ln;
#pragma unroll
                    for (int ni = 0; ni < 4; ni++) Cp[ni * 16] = f2bf(o0[ni]);
                }
            } else {
                // v: transposed scatter into Vtg[(b*NKV+g)*HD+d][s]
                const int g2 = (colw - (H_ + NKV_ * HD_)) >> 6;
                const int rbase = row0 + wr * 16 + qd * 4;
                const int bg2 = ((rbase >> 11) * NKV_) + g2;
                const int s0 = rbase & (S_ - 1);
#pragma unroll
                for (int ni = 0; ni < 4; ni++) {
                    const int d = ni * 16 + ln;
                    short4 pk = { f2bf(acc[ni][0]), f2bf(acc[ni][1]),
                                  f2bf(acc[ni][2]), f2bf(acc[ni][3]) };
                    *(short4*)&Vtg[((size_t)bg2 * HD_ + d) * S_ + s0] = pk;
                }
            }
            __syncthreads();   // epilogue done before next tile's prologue writes
        }
    }
    grid.sync();

    // ======================= Phase 2: attention (v17 verbatim) =============
    {
        const int fid = bid;             // 0..255
        const int bg  = fid & 7;         // b*NKV+g
        const int u   = fid >> 3;        // 0..31
        const int b   = bg >> 2;
        const int g   = bg & 3;
        const int h   = g * R_ + (u & 3);
        const int a   = u >> 2;          // pair index 0..7

        short* const ps = sm.at.Ps[w];

        const short* const Kb = qkv + (size_t)b * S_ * QKVW + H_ + g * HD_;
        const short* const Vb = Vtg + (size_t)bg * HD_ * S_;
        const float* const mb = maskb + b * S_;

        const int fr = tid >> 3;         // 0..63 (staging row)
        const int fc = (tid & 7) * 8;    // staging col (elements)

#pragma unroll 1
        for (int ph = 0; ph < 2; ph++) {
            const int qt   = ph ? (15 - a) : a;
            const int rowb = qt * 128 + w * 16;   // this wave's 16-row strip
            const int ktd  = 2 * qt + (w >> 2);   // wave's diagonal tile
            const int ntp  = 2 * qt + 2;          // tiles this phase
            const int qrow = rowb + ln;

            bf16x8 qf0, qf1;
            {
                const short* qp = qkv + (size_t)(b * S_ + rowb + ln) * QKVW + h * HD_;
                qf0 = *(const bf16x8*)&qp[qd * 8];
                qf1 = *(const bf16x8*)&qp[32 + qd * 8];
            }

            f32x4 O[4] = {};
            float mrow = -1e30f, lrow = 0.0f;    // mrow in log2 units

            __syncthreads();   // protect Ks/Vt from previous phase's readers
            *(bf16x8*)&sm.at.Ks[0][fr * 72 + fc] = *(const bf16x8*)&Kb[(size_t)fr * QKVW + fc];
            *(bf16x8*)&sm.at.Vt[0][fr * 72 + fc] = *(const bf16x8*)&Vb[(size_t)fr * S_ + fc];
            if (tid < 64) sm.at.mskS[0][tid] = (1.0f - mb[tid]) * (-1e9f * LOG2E);
            __syncthreads();

            int cur = 0;
#pragma unroll 1
            for (int kt = 0; kt < ntp; kt++) {
                const int base = kt * 64;
                const bool pf = (kt + 1 < ntp);

                bf16x8 pk, pv;
                float pm = 0.0f;
                if (pf) {
                    const int nb = base + 64;
                    pk = *(const bf16x8*)&Kb[(size_t)(nb + fr) * QKVW + fc];
                    pv = *(const bf16x8*)&Vb[(size_t)fr * S_ + nb + fc];
                    if (tid < 64) pm = (1.0f - mb[nb + tid]) * (-1e9f * LOG2E);
                }

                if (kt <= ktd) {   // wave-uniform
                    f32x4 St[4];
#pragma unroll
                    for (int kg = 0; kg < 4; kg++) {
                        bf16x8 ka0 = *(const bf16x8*)&sm.at.Ks[cur][(kg * 16 + ln) * 72 + qd * 8];
                        bf16x8 ka1 = *(const bf16x8*)&sm.at.Ks[cur][(kg * 16 + ln) * 72 + 32 + qd * 8];
                        f32x4 z = {0.f, 0.f, 0.f, 0.f};
                        z = __builtin_amdgcn_mfma_f32_16x16x32_bf16(ka0, qf0, z, 0, 0, 0);
                        St[kg] = __builtin_amdgcn_mfma_f32_16x16x32_bf16(ka1, qf1, z, 0, 0, 0);
                    }

                    bf16x8 vb[2][4];
#pragma unroll
                    for (int kc2 = 0; kc2 < 2; kc2++)
#pragma unroll
                        for (int dt = 0; dt < 4; dt++)
                            vb[kc2][dt] = *(const bf16x8*)&sm.at.Vt[cur][(dt * 16 + ln) * 72 + kc2 * 32 + qd * 8];

                    float sc[4][4];
#pragma unroll
                    for (int kg = 0; kg < 4; kg++) {
                        float4 mv = *(const float4*)&sm.at.mskS[cur][kg * 16 + qd * 4];
                        sc[kg][0] = fmaf(St[kg][0], 0.125f * LOG2E, mv.x);
                        sc[kg][1] = fmaf(St[kg][1], 0.125f * LOG2E, mv.y);
                        sc[kg][2] = fmaf(St[kg][2], 0.125f * LOG2E, mv.z);
                        sc[kg][3] = fmaf(St[kg][3], 0.125f * LOG2E, mv.w);
                    }
                    if (kt == ktd) {
#pragma unroll
                        for (int kg = 0; kg < 4; kg++) {
                            const int keyb = base + kg * 16 + qd * 4;
#pragma unroll
                            for (int i = 0; i < 4; i++)
                                if (keyb + i > qrow) sc[kg][i] = -1e30f;
                        }
                    }

                    float mx = sc[0][0];
#pragma unroll
                    for (int kg = 0; kg < 4; kg++)
#pragma unroll
                        for (int i = 0; i < 4; i++) mx = fmaxf(mx, sc[kg][i]);
                    mx = fmaxf(mx, __shfl_xor(mx, 16));
                    mx = fmaxf(mx, __shfl_xor(mx, 32));

                    if (__ballot(mx > mrow + 11.5416f)) {
                        float nm    = fmaxf(mrow, mx);
                        float alpha = exp2fast(mrow - nm);
                        lrow *= alpha;
#pragma unroll
                        for (int i = 0; i < 4; i++) {
                            float av = __shfl(alpha, qd * 4 + i);
#pragma unroll
                            for (int dt = 0; dt < 4; dt++) O[dt][i] *= av;
                        }
                        mrow = nm;
                    }
                    const float nm = mrow;

                    float ls = 0.0f;
#pragma unroll
                    for (int kg = 0; kg < 4; kg++)
#pragma unroll
                        for (int i = 0; i < 4; i++) {
                            float p = exp2fast(sc[kg][i] - nm);
                            sc[kg][i] = p;
                            ls += p;
                        }
                    ls += __shfl_xor(ls, 16);
                    ls += __shfl_xor(ls, 32);
                    lrow += ls;

#pragma unroll
                    for (int kg = 0; kg < 4; kg++) {
                        uint2 pw;
                        pw.x = cvt_pk_bf16(sc[kg][0], sc[kg][1]);
                        pw.y = cvt_pk_bf16(sc[kg][2], sc[kg][3]);
                        *(uint2*)&ps[ln * 72 + kg * 16 + qd * 4] = pw;
                    }

#pragma unroll
                    for (int kc2 = 0; kc2 < 2; kc2++) {
                        bf16x8 pa = *(const bf16x8*)&ps[ln * 72 + kc2 * 32 + qd * 8];
#pragma unroll
                        for (int dt = 0; dt < 4; dt++)
                            O[dt] = __builtin_amdgcn_mfma_f32_16x16x32_bf16(pa, vb[kc2][dt], O[dt], 0, 0, 0);
                    }
                }

                if (pf) {
                    const int nxt = cur ^ 1;
                    *(bf16x8*)&sm.at.Ks[nxt][fr * 72 + fc] = pk;
                    *(bf16x8*)&sm.at.Vt[nxt][fr * 72 + fc] = pv;
                    if (tid < 64) sm.at.mskS[nxt][tid] = pm;
                }
                __syncthreads();
                cur ^= 1;
            }

            // finalize this phase: write bf16 into q-slice
#pragma unroll
            for (int i = 0; i < 4; i++) {
                float li  = __shfl(lrow, qd * 4 + i);
                float inv = 1.0f / li;
                const int row = rowb + qd * 4 + i;
                short* op = qkv + (size_t)(b * S_ + row) * QKVW + h * HD_ + ln;
#pragma unroll
                for (int dt = 0; dt < 4; dt++) op[dt * 16] = f2bf(O[dt][i] * inv);
            }
        }
    }
    grid.sync();

    // ======================= Phase 3: GEMM2 (out = attn @ Wot^T) ===========
    {
        const int wr = w >> 1;           // 0..3
        const int wc = w & 1;            // 0..1
        const int sr = lane >> 2, sk = (lane & 3) * 8;

        for (int tile = bid; tile < 512; tile += 256) {
            const int row0 = (tile / 8) * 64;
            const int col0 = (tile % 8) * 128;

            f32x4 acc[4];
#pragma unroll
            for (int ni = 0; ni < 4; ni++) acc[ni] = (f32x4){0.f, 0.f, 0.f, 0.f};

            const short* ap = qkv + (size_t)(row0 + (w & 3) * 16 + sr) * QKVW + sk;
            const short* bp = Wot + (size_t)(col0 + w * 16 + sr) * 1024 + sk;

            if (w < 4) gload_lds16(ap, &sm.g.Ah[0][((w & 3) * 16) * 32]);
            gload_lds16(bp, &sm.g.Bh[0][(w * 16) * 32]);
            __syncthreads();

            for (int t = 0; t < 32; t++) {
                const int cur = t & 1, nxt = cur ^ 1;
                if (t + 1 < 32) {
                    const int k1 = (t + 1) * 32;
                    if (w < 4) gload_lds16(ap + k1, &sm.g.Ah[nxt][((w & 3) * 16) * 32]);
                    gload_lds16(bp + k1, &sm.g.Bh[nxt][(w * 16) * 32]);
                }
                bf16x8 af = *(const bf16x8*)&sm.g.Ah[cur][(wr * 16 + ln) * 32 + qd * 8];
                bf16x8 bfr[4];
#pragma unroll
                for (int ni = 0; ni < 4; ni++)
                    bfr[ni] = *(const bf16x8*)&sm.g.Bh[cur][(wc * 64 + ni * 16 + ln) * 32 + qd * 8];
#pragma unroll
                for (int ni = 0; ni < 4; ni++)
                    acc[ni] = __builtin_amdgcn_mfma_f32_16x16x32_bf16(af, bfr[ni], acc[ni], 0, 0, 0);
                __syncthreads();
            }

#pragma unroll
            for (int i = 0; i < 4; i++) {
                const size_t row = row0 + wr * 16 + qd * 4 + i;
                float* Cp = out + row * 1024 + col0 + wc * 64 + ln;
#pragma unroll
                for (int ni = 0; ni < 4; ni++) Cp[ni * 16] = acc[ni][i];
            }
            __syncthreads();   // before next tile's prologue overwrites LDS
        }
    }
}

// ---------------------------------------------------------------------------
extern "C" void kernel_launch(void* const* d_in, const int* in_sizes, int n_in,
                              void* d_out, int out_size, void* d_ws, size_t ws_size,
                              hipStream_t stream) {
    const float* x     = (const float*)d_in[0];
    const float* cosb  = (const float*)d_in[1];
    const float* sinb  = (const float*)d_in[2];
    const float* maskb = (const float*)d_in[3];
    const float* Wq    = (const float*)d_in[4];
    const float* Wk    = (const float*)d_in[5];
    const float* Wv    = (const float*)d_in[6];
    const float* Wo    = (const float*)d_in[7];

    const int M = B_ * S_;   // 4096

    // ws: qkv | Wqkvt | Wot | Vtg  (19.9 MB bf16). d_out only for out.
    short* qkv   = (short*)d_ws;                     // [4096][1536]
    short* Wqkvt = qkv + (size_t)M * QKVW;           // [1536][1024]
    short* Wot   = Wqkvt + (size_t)QKVW * H_;        // [1024][1024]
    short* Vtg   = Wot + (size_t)H_ * H_;            // [8*64][2048]
    float* out   = (float*)d_out;

    void* args[] = { (void*)&x, (void*)&cosb, (void*)&sinb, (void*)&maskb,
                     (void*)&Wq, (void*)&Wk, (void*)&Wv, (void*)&Wo,
                     (void*)&qkv, (void*)&Wqkvt, (void*)&Wot, (void*)&Vtg,
                     (void*)&out };

    hipLaunchCooperativeKernel((const void*)mega, dim3(256), dim3(512),
                               args, 0, stream);
}

// Round 12
// 206.805 us; speedup vs baseline: 2.3991x; 2.3991x over previous
//
#include <hip/hip_runtime.h>
#include <math.h>

#define B_   2
#define S_   2048
#define H_   1024
#define NH_  16
#define NKV_ 4
#define HD_  64
#define R_   (NH_ / NKV_)   // 4 q-heads per kv-head
#define QKVW 1536           // qkv row width (q 0..1023 | k 1024..1279 | v 1280..1535)

typedef __attribute__((ext_vector_type(8))) short bf16x8;
typedef __attribute__((ext_vector_type(4))) float f32x4;

__device__ inline short f2bf(float f) {
    unsigned u = __float_as_uint(f);
    u += 0x7FFF + ((u >> 16) & 1);     // RNE to bf16
    return (short)(u >> 16);
}

__device__ inline float exp2fast(float x) {
#if __has_builtin(__builtin_amdgcn_exp2f)
    return __builtin_amdgcn_exp2f(x);
#else
    float r; asm volatile("v_exp_f32 %0, %1\n\ts_nop 1" : "=v"(r) : "v"(x)); return r;
#endif
}

__device__ inline unsigned cvt_pk_bf16(float lo, float hi) {
    unsigned r;
    asm("v_cvt_pk_bf16_f32 %0, %1, %2" : "=v"(r) : "v"(lo), "v"(hi));
    return r;
}

#define LOG2E 1.4426950408889634f

// async global->LDS, 16 B per lane (m97/m104 semantics).
__device__ inline void gload_lds16(const void* gptr, void* lptr) {
    __builtin_amdgcn_global_load_lds(
        (const __attribute__((address_space(1))) unsigned int*)gptr,
        (__attribute__((address_space(3))) unsigned int*)lptr,
        16, 0, 0);
}

// ---------------------------------------------------------------------------
// Weight transposes. 640 blocks of 64x64 tiles (R10-proven).
// ---------------------------------------------------------------------------
__global__ __launch_bounds__(256) void tconv_all(const float* __restrict__ Wq,
                                                 const float* __restrict__ Wk,
                                                 const float* __restrict__ Wv,
                                                 const float* __restrict__ Wo,
                                                 short* __restrict__ Wqkvt,
                                                 short* __restrict__ Wot) {
    __shared__ short T[64][68];
    const int bx = blockIdx.x;
    const int tid = threadIdx.x;
    const float* W; short* Wt; int N, idx;
    if (bx < 256)      { W = Wq; Wt = Wqkvt;                     N = 1024; idx = bx; }
    else if (bx < 320) { W = Wk; Wt = Wqkvt + 1024 * 1024;       N = 256;  idx = bx - 256; }
    else if (bx < 384) { W = Wv; Wt = Wqkvt + 1280 * 1024;       N = 256;  idx = bx - 320; }
    else               { W = Wo; Wt = Wot;                       N = 1024; idx = bx - 384; }
    const int ntiles = N >> 6;
    const int n0 = (idx % ntiles) * 64;
    const int k0 = (idx / ntiles) * 64;

    const int r  = tid >> 4;
    const int c4 = (tid & 15) * 4;
#pragma unroll
    for (int t = 0; t < 4; t++) {
        int row = t * 16 + r;
        float4 v = *(const float4*)&W[(size_t)(k0 + row) * N + n0 + c4];
        T[c4 + 0][row] = f2bf(v.x);
        T[c4 + 1][row] = f2bf(v.y);
        T[c4 + 2][row] = f2bf(v.z);
        T[c4 + 3][row] = f2bf(v.w);
    }
    __syncthreads();
#pragma unroll
    for (int t = 0; t < 4; t++) {
        int row = t * 16 + r;          // n index
        short4 o = *(short4*)&T[row][c4];
        *(short4*)&Wt[(size_t)(n0 + row) * 1024 + k0 + c4] = o;
    }
}

// ---------------------------------------------------------------------------
// Fused GEMM1 (R10-proven): qkv = bf16(x) @ Wqkvt^T, 64x128 tile, BK=32,
// 2-phase dbuf, fused fp32->bf16 A-convert. RoPE epilogue q/k; v scatter.
// ---------------------------------------------------------------------------
__global__ __launch_bounds__(256) void gemm1_fused(const float* __restrict__ x,
                                                   const short* __restrict__ Bt,
                                                   short* __restrict__ qkv,
                                                   short* __restrict__ Vtg,
                                                   const float* __restrict__ cosb,
                                                   const float* __restrict__ sinb) {
    __shared__ short Ah[2][64 * 32];    // 2 x 4 KB
    __shared__ short Bh[2][128 * 32];   // 2 x 8 KB

    const int tid  = threadIdx.x;
    const int w    = tid >> 6;
    const int lane = tid & 63;
    const int ln   = lane & 15;
    const int qd   = lane >> 4;
    const int wr   = w >> 1, wc = w & 1;
    const int row0 = blockIdx.y * 64;
    const int col0 = blockIdx.x * 128;

    const int sr = lane >> 2;        // 0..15 staging row-in-chunk
    const int sk = (lane & 3) * 8;   // k element offset
    const int ar  = tid >> 2;        // 0..63 A-convert row
    const int ac8 = (tid & 3) * 8;   // 0,8,16,24

    const float* xp  = x + (size_t)(row0 + ar) * 1024 + ac8;
    const short* bp0 = Bt + (size_t)(col0 + w * 32 + sr) * 1024 + sk;
    const short* bp1 = Bt + (size_t)(col0 + w * 32 + 16 + sr) * 1024 + sk;

    f32x4 acc[2][4];
#pragma unroll
    for (int mi = 0; mi < 2; mi++)
#pragma unroll
        for (int ni = 0; ni < 4; ni++)
            acc[mi][ni] = (f32x4){0.f, 0.f, 0.f, 0.f};

    // prologue: stage tile 0 into buf 0
    {
        float4 a1 = *(const float4*)xp;
        float4 a2 = *(const float4*)(xp + 4);
        bf16x8 o;
        o[0]=f2bf(a1.x); o[1]=f2bf(a1.y); o[2]=f2bf(a1.z); o[3]=f2bf(a1.w);
        o[4]=f2bf(a2.x); o[5]=f2bf(a2.y); o[6]=f2bf(a2.z); o[7]=f2bf(a2.w);
        *(bf16x8*)&Ah[0][ar * 32 + ac8] = o;
    }
    gload_lds16(bp0, &Bh[0][(w * 32) * 32]);
    gload_lds16(bp1, &Bh[0][(w * 32 + 16) * 32]);
    __syncthreads();

    for (int t = 0; t < 32; t++) {
        const int cur = t & 1, nxt = cur ^ 1;
        if (t + 1 < 32) {   // stage next tile first (overlaps MFMA below)
            const int k1 = (t + 1) * 32;
            gload_lds16(bp0 + k1, &Bh[nxt][(w * 32) * 32]);
            gload_lds16(bp1 + k1, &Bh[nxt][(w * 32 + 16) * 32]);
            float4 a1 = *(const float4*)(xp + k1);
            float4 a2 = *(const float4*)(xp + k1 + 4);
            bf16x8 o;
            o[0]=f2bf(a1.x); o[1]=f2bf(a1.y); o[2]=f2bf(a1.z); o[3]=f2bf(a1.w);
            o[4]=f2bf(a2.x); o[5]=f2bf(a2.y); o[6]=f2bf(a2.z); o[7]=f2bf(a2.w);
            *(bf16x8*)&Ah[nxt][ar * 32 + ac8] = o;
        }

        bf16x8 af[2], bfr[4];
#pragma unroll
        for (int mi = 0; mi < 2; mi++)
            af[mi] = *(const bf16x8*)&Ah[cur][(wr * 32 + mi * 16 + ln) * 32 + qd * 8];
#pragma unroll
        for (int ni = 0; ni < 4; ni++)
            bfr[ni] = *(const bf16x8*)&Bh[cur][(wc * 64 + ni * 16 + ln) * 32 + qd * 8];
#pragma unroll
        for (int mi = 0; mi < 2; mi++)
#pragma unroll
            for (int ni = 0; ni < 4; ni++)
                acc[mi][ni] = __builtin_amdgcn_mfma_f32_16x16x32_bf16(af[mi], bfr[ni], acc[mi][ni], 0, 0, 0);

        __syncthreads();   // drain lands after the MFMAs
    }

    const int colw = col0 + wc * 64;          // this wave's 64-col half
    if (colw < H_ + NKV_ * HD_) {
        // ---- q or k columns: RoPE in fp32, store bf16 to qkv ----
#pragma unroll
        for (int mi = 0; mi < 2; mi++)
#pragma unroll
            for (int i = 0; i < 4; i++) {
                const int row  = row0 + wr * 32 + mi * 16 + qd * 4 + i;
                const int spos = row & (S_ - 1);
                const float* cp = cosb + (size_t)spos * HD_;
                const float* sp = sinb + (size_t)spos * HD_;
                float o0[4];
#pragma unroll
                for (int ni = 0; ni < 2; ni++) {
                    const int d = ni * 16 + ln;
                    float x0 = acc[mi][ni][i], x1 = acc[mi][ni + 2][i];
                    o0[ni]     = x0 * cp[d]      - x1 * sp[d];
                    o0[ni + 2] = x1 * cp[d + 32] + x0 * sp[d + 32];
                }
                short* Cp = qkv + (size_t)row * QKVW + colw + ln;
#pragma unroll
                for (int ni = 0; ni < 4; ni++) Cp[ni * 16] = f2bf(o0[ni]);
            }
    } else {
        // ---- v columns: transposed scatter into Vtg[(b*NKV+g)*HD+d][s] ----
        const int g = (colw - (H_ + NKV_ * HD_)) >> 6;
#pragma unroll
        for (int mi = 0; mi < 2; mi++) {
            const int rbase = row0 + wr * 32 + mi * 16 + qd * 4;   // i = +0..3
            const int bg = ((rbase >> 11) * NKV_) + g;
            const int s0 = rbase & (S_ - 1);
#pragma unroll
            for (int ni = 0; ni < 4; ni++) {
                const int d = ni * 16 + ln;
                short4 pk = { f2bf(acc[mi][ni][0]), f2bf(acc[mi][ni][1]),
                              f2bf(acc[mi][ni][2]), f2bf(acc[mi][ni][3]) };
                *(short4*)&Vtg[((size_t)bg * HD_ + d) * S_ + s0] = pk;
            }
        }
    }
}

// ---------------------------------------------------------------------------
// bf16 MFMA GEMM (R10-proven), B^T form: C = A @ Bt^T, 64x128, 2-phase dbuf.
// ---------------------------------------------------------------------------
__global__ __launch_bounds__(256) void gemm2_bt(const short* __restrict__ A, int lda,
                                                const short* __restrict__ Bt,
                                                float* __restrict__ C, int ldc,
                                                int K) {
    __shared__ short Ah[2][64 * 32];
    __shared__ short Bh[2][128 * 32];

    const int tid  = threadIdx.x;
    const int w    = tid >> 6;
    const int lane = tid & 63;
    const int ln   = lane & 15;
    const int qd   = lane >> 4;
    const int wr   = w >> 1, wc = w & 1;
    const int row0 = blockIdx.y * 64;
    const int col0 = blockIdx.x * 128;

    const int sr = lane >> 2;
    const int sk = (lane & 3) * 8;

    const short* ap  = A + (size_t)(row0 + w * 16 + sr) * lda + sk;
    const short* bp0 = Bt + (size_t)(col0 + w * 32 + sr) * K + sk;
    const short* bp1 = Bt + (size_t)(col0 + w * 32 + 16 + sr) * K + sk;

    f32x4 acc[2][4];
#pragma unroll
    for (int mi = 0; mi < 2; mi++)
#pragma unroll
        for (int ni = 0; ni < 4; ni++)
            acc[mi][ni] = (f32x4){0.f, 0.f, 0.f, 0.f};

    const int nt = K >> 5;
    gload_lds16(ap,  &Ah[0][(w * 16) * 32]);
    gload_lds16(bp0, &Bh[0][(w * 32) * 32]);
    gload_lds16(bp1, &Bh[0][(w * 32 + 16) * 32]);
    __syncthreads();

    for (int t = 0; t < nt; t++) {
        const int cur = t & 1, nxt = cur ^ 1;
        if (t + 1 < nt) {
            const int k1 = (t + 1) * 32;
            gload_lds16(ap + k1,  &Ah[nxt][(w * 16) * 32]);
            gload_lds16(bp0 + k1, &Bh[nxt][(w * 32) * 32]);
            gload_lds16(bp1 + k1, &Bh[nxt][(w * 32 + 16) * 32]);
        }

        bf16x8 af[2], bfr[4];
#pragma unroll
        for (int mi = 0; mi < 2; mi++)
            af[mi] = *(const bf16x8*)&Ah[cur][(wr * 32 + mi * 16 + ln) * 32 + qd * 8];
#pragma unroll
        for (int ni = 0; ni < 4; ni++)
            bfr[ni] = *(const bf16x8*)&Bh[cur][(wc * 64 + ni * 16 + ln) * 32 + qd * 8];
#pragma unroll
        for (int mi = 0; mi < 2; mi++)
#pragma unroll
            for (int ni = 0; ni < 4; ni++)
                acc[mi][ni] = __builtin_amdgcn_mfma_f32_16x16x32_bf16(af[mi], bfr[ni], acc[mi][ni], 0, 0, 0);

        __syncthreads();
    }

#pragma unroll
    for (int mi = 0; mi < 2; mi++)
#pragma unroll
        for (int i = 0; i < 4; i++) {
            const size_t row = row0 + wr * 32 + mi * 16 + qd * 4 + i;
            float* Cp = C + row * ldc + col0 + wc * 64 + ln;
#pragma unroll
            for (int ni = 0; ni < 4; ni++) Cp[ni * 16] = acc[mi][ni][i];
        }
}

// ---------------------------------------------------------------------------
// bf16 MFMA flash attention v19: de-synced 2-blocks/CU.
//   v17's 8-wave block was barrier-locked into one burst phase (QK-MFMA,
//   then softmax-VALU, then PV) -> the 2 waves/SIMD could never overlap
//   opposite pipes (MfmaUtil 11.5 + VALUBusy 27, both low). v19 splits each
//   pair-block into TWO independent 256-thread blocks (one q-tile, 4 waves
//   x 32-row strips = v15's verified inner body + v17's log2/cvt_pk/
//   pre-biased-mask). Grid 512, LDS 46.6 KB -> 2 blocks/CU, phases drift
//   -> one block's VALU fills the other's MFMA gaps (m114).
//   Mapping: i&7 = bg (XCD affinity); u=i>>3: hr=u&3, t=(u>>2)&7,
//   slot=u>>5; qt = slot ? 15-t : t. Breadth-first dispatch puts u and
//   u+32 (qt = t and 15-t) on the same CU -> 34 tiles/CU uniform.
//   T5 setprio around MFMA clusters (m191: helps independent-block attn).
// ---------------------------------------------------------------------------
__global__ __launch_bounds__(256) void attn_kernel(short* __restrict__ qkv,
                                                   const short* __restrict__ Vtg,
                                                   const float* __restrict__ maskb) {
    const int tid  = threadIdx.x;
    const int w    = tid >> 6;           // 0..3
    const int lane = tid & 63;
    const int ln   = lane & 15;
    const int qd   = lane >> 4;

    const int i   = blockIdx.x;          // 0..511
    const int bg  = i & 7;               // b*NKV+g -> XCD
    const int u   = i >> 3;              // 0..63
    const int b   = bg >> 2;
    const int g   = bg & 3;
    const int hr  = u & 3;
    const int t   = (u >> 2) & 7;
    const int slot = u >> 5;             // 0..1
    const int h   = g * R_ + hr;
    const int qt  = slot ? (15 - t) : t; // 0..15

    __shared__ short Ks[2][64 * 72];     // K  [key][dim], stride 72
    __shared__ short Vt[2][64 * 72];     // V^T [dim][key]
    __shared__ short Ps[4][16 * 72];     // per-wave P round-trip (one rg)
    __shared__ float mskS[2][64];        // pre-biased+scaled mask
    short* const ps = Ps[w];

    const short* const Kb = qkv + (size_t)b * S_ * QKVW + H_ + g * HD_;
    const short* const Vb = Vtg + (size_t)bg * HD_ * S_;
    const float* const mb = maskb + b * S_;

    const int fr = tid >> 2;             // 0..63 (staging row)
    const int fc = (tid & 3) * 16;       // staging col (shorts): 0,16,32,48

    const int rowb = qt * 128 + w * 32;  // wave's first q-row
    const int ktd  = 2 * qt + (w >> 1);  // wave's diagonal (last) tile
    const int nt   = 2 * qt + 2;         // 64-key tiles staged by this block

    // ---- Q B-frags: rows rowb+rg*16+ln ----
    bf16x8 qf[2][2];
#pragma unroll
    for (int rg = 0; rg < 2; rg++) {
        const short* qp = qkv + (size_t)(b * S_ + rowb + rg * 16 + ln) * QKVW + h * HD_;
        qf[rg][0] = *(const bf16x8*)&qp[qd * 8];
        qf[rg][1] = *(const bf16x8*)&qp[32 + qd * 8];
    }

    f32x4 O[2][4] = {};
    float mrow[2] = {-1e30f, -1e30f};    // log2 units
    float lrow[2] = {0.0f, 0.0f};

    // ---- stage tile 0 (2 x 16B chunks per thread) ----
    *(bf16x8*)&Ks[0][fr * 72 + fc]     = *(const bf16x8*)&Kb[(size_t)fr * QKVW + fc];
    *(bf16x8*)&Ks[0][fr * 72 + fc + 8] = *(const bf16x8*)&Kb[(size_t)fr * QKVW + fc + 8];
    *(bf16x8*)&Vt[0][fr * 72 + fc]     = *(const bf16x8*)&Vb[(size_t)fr * S_ + fc];
    *(bf16x8*)&Vt[0][fr * 72 + fc + 8] = *(const bf16x8*)&Vb[(size_t)fr * S_ + fc + 8];
    if (tid < 64) mskS[0][tid] = (1.0f - mb[tid]) * (-1e9f * LOG2E);
    __syncthreads();

    int cur = 0;
#pragma unroll 1
    for (int kt = 0; kt < nt; kt++) {
        const int base = kt * 64;
        const bool pf = (kt + 1 < nt);

        // ---- prefetch tile kt+1 into registers (no wait) ----
        bf16x8 pk0, pk1, pv0, pv1;
        float pm = 0.0f;
        if (pf) {
            const int nb = base + 64;
            pk0 = *(const bf16x8*)&Kb[(size_t)(nb + fr) * QKVW + fc];
            pk1 = *(const bf16x8*)&Kb[(size_t)(nb + fr) * QKVW + fc + 8];
            pv0 = *(const bf16x8*)&Vb[(size_t)fr * S_ + nb + fc];
            pv1 = *(const bf16x8*)&Vb[(size_t)fr * S_ + nb + fc + 8];
            if (tid < 64) pm = (1.0f - mb[nb + tid]) * (-1e9f * LOG2E);
        }

        if (kt <= ktd) {   // wave-uniform: tile has unmasked keys
            // ---- QK^T swapped: St[rg][kg] = S^T tile ----
            f32x4 St[2][4];
            __builtin_amdgcn_s_setprio(1);
#pragma unroll
            for (int kg = 0; kg < 4; kg++) {
                bf16x8 ka0 = *(const bf16x8*)&Ks[cur][(kg * 16 + ln) * 72 + qd * 8];
                bf16x8 ka1 = *(const bf16x8*)&Ks[cur][(kg * 16 + ln) * 72 + 32 + qd * 8];
#pragma unroll
                for (int rg = 0; rg < 2; rg++) {
                    f32x4 z = {0.f, 0.f, 0.f, 0.f};
                    z = __builtin_amdgcn_mfma_f32_16x16x32_bf16(ka0, qf[rg][0], z, 0, 0, 0);
                    St[rg][kg] = __builtin_amdgcn_mfma_f32_16x16x32_bf16(ka1, qf[rg][1], z, 0, 0, 0);
                }
            }
            __builtin_amdgcn_s_setprio(0);

            // ---- V B-frags from LDS (shared across rgs) ----
            bf16x8 vb[2][4];
#pragma unroll
            for (int kc2 = 0; kc2 < 2; kc2++)
#pragma unroll
                for (int dt = 0; dt < 4; dt++)
                    vb[kc2][dt] = *(const bf16x8*)&Vt[cur][(dt * 16 + ln) * 72 + kc2 * 32 + qd * 8];

            // ---- pre-biased mask (log2-scaled) ----
            float mt[4][4];
#pragma unroll
            for (int kg = 0; kg < 4; kg++) {
                float4 mv = *(const float4*)&mskS[cur][kg * 16 + qd * 4];
                mt[kg][0] = mv.x; mt[kg][1] = mv.y; mt[kg][2] = mv.z; mt[kg][3] = mv.w;
            }

            const bool diag = (kt == ktd);

            // ---- per rg: log2 softmax -> cvt_pk pack -> PV ----
#pragma unroll
            for (int rg = 0; rg < 2; rg++) {
                const int qrow = rowb + rg * 16 + ln;
                float sc[4][4];
#pragma unroll
                for (int kg = 0; kg < 4; kg++) {
                    const int keyb = base + kg * 16 + qd * 4;
#pragma unroll
                    for (int i2 = 0; i2 < 4; i2++) {
                        float v = fmaf(St[rg][kg][i2], 0.125f * LOG2E, mt[kg][i2]);
                        sc[kg][i2] = (diag && (keyb + i2 > qrow)) ? -1e30f : v;
                    }
                }
                float mx = sc[0][0];
#pragma unroll
                for (int kg = 0; kg < 4; kg++)
#pragma unroll
                    for (int i2 = 0; i2 < 4; i2++) mx = fmaxf(mx, sc[kg][i2]);
                mx = fmaxf(mx, __shfl_xor(mx, 16));
                mx = fmaxf(mx, __shfl_xor(mx, 32));

                // defer-max (T13): 8 ln-units = 11.5416 log2-units
                if (__ballot(mx > mrow[rg] + 11.5416f)) {
                    float nm    = fmaxf(mrow[rg], mx);
                    float alpha = exp2fast(mrow[rg] - nm);
                    lrow[rg] *= alpha;
#pragma unroll
                    for (int i2 = 0; i2 < 4; i2++) {
                        float av = __shfl(alpha, qd * 4 + i2);
#pragma unroll
                        for (int dt = 0; dt < 4; dt++) O[rg][dt][i2] *= av;
                    }
                    mrow[rg] = nm;
                }
                const float nm = mrow[rg];

                float ls = 0.0f;
#pragma unroll
                for (int kg = 0; kg < 4; kg++)
#pragma unroll
                    for (int i2 = 0; i2 < 4; i2++) {
                        float p = exp2fast(sc[kg][i2] - nm);
                        sc[kg][i2] = p;
                        ls += p;
                    }
                ls += __shfl_xor(ls, 16);
                ls += __shfl_xor(ls, 32);
                lrow[rg] += ls;

#pragma unroll
                for (int kg = 0; kg < 4; kg++) {
                    uint2 pw;
                    pw.x = cvt_pk_bf16(sc[kg][0], sc[kg][1]);
                    pw.y = cvt_pk_bf16(sc[kg][2], sc[kg][3]);
                    *(uint2*)&ps[ln * 72 + kg * 16 + qd * 4] = pw;
                }

                // PV: O[rg] += P[rg] @ V (same-wave LDS write->read, in order)
                __builtin_amdgcn_s_setprio(1);
#pragma unroll
                for (int kc2 = 0; kc2 < 2; kc2++) {
                    bf16x8 pa = *(const bf16x8*)&ps[ln * 72 + kc2 * 32 + qd * 8];
#pragma unroll
                    for (int dt = 0; dt < 4; dt++)
                        O[rg][dt] = __builtin_amdgcn_mfma_f32_16x16x32_bf16(pa, vb[kc2][dt], O[rg][dt], 0, 0, 0);
                }
                __builtin_amdgcn_s_setprio(0);
            }
        }

        // ---- write prefetched tile into the other buffer ----
        if (pf) {
            const int nxt = cur ^ 1;
            *(bf16x8*)&Ks[nxt][fr * 72 + fc]     = pk0;
            *(bf16x8*)&Ks[nxt][fr * 72 + fc + 8] = pk1;
            *(bf16x8*)&Vt[nxt][fr * 72 + fc]     = pv0;
            *(bf16x8*)&Vt[nxt][fr * 72 + fc + 8] = pv1;
            if (tid < 64) mskS[nxt][tid] = pm;
        }
        __syncthreads();
        cur ^= 1;
    }

    // ---- finalize: l replicated over qd; write bf16 into q-slice ----
#pragma unroll
    for (int rg = 0; rg < 2; rg++)
#pragma unroll
        for (int i2 = 0; i2 < 4; i2++) {
            float li  = __shfl(lrow[rg], qd * 4 + i2);
            float inv = 1.0f / li;
            const int row = rowb + rg * 16 + qd * 4 + i2;
            short* op = qkv + (size_t)(b * S_ + row) * QKVW + h * HD_ + ln;
#pragma unroll
            for (int dt = 0; dt < 4; dt++) op[dt * 16] = f2bf(O[rg][dt][i2] * inv);
        }
}

// ---------------------------------------------------------------------------
extern "C" void kernel_launch(void* const* d_in, const int* in_sizes, int n_in,
                              void* d_out, int out_size, void* d_ws, size_t ws_size,
                              hipStream_t stream) {
    const float* x     = (const float*)d_in[0];
    const float* cosb  = (const float*)d_in[1];
    const float* sinb  = (const float*)d_in[2];
    const float* maskb = (const float*)d_in[3];
    const float* Wq    = (const float*)d_in[4];
    const float* Wk    = (const float*)d_in[5];
    const float* Wv    = (const float*)d_in[6];
    const float* Wo    = (const float*)d_in[7];

    const int M = B_ * S_;   // 4096

    // ws: qkv | Wqkvt | Wot | Vtg  (19.9 MB bf16). d_out only for out.
    short* qkv   = (short*)d_ws;                     // [4096][1536]
    short* Wqkvt = qkv + (size_t)M * QKVW;           // [1536][1024]
    short* Wot   = Wqkvt + (size_t)QKVW * H_;        // [1024][1024]
    short* Vtg   = Wot + (size_t)H_ * H_;            // [8*64][2048]
    float* out   = (float*)d_out;

    dim3 blk(256);

    // weight transposes
    tconv_all<<<dim3(640), blk, 0, stream>>>(Wq, Wk, Wv, Wo, Wqkvt, Wot);

    // GEMM1 fused (64x128, 2-phase dbuf, fused A-convert)
    gemm1_fused<<<dim3(QKVW / 128, M / 64), blk, 0, stream>>>(x, Wqkvt, qkv, Vtg, cosb, sinb);

    // attention: 512 q-tile blocks x 256 threads, 2 de-synced blocks/CU
    attn_kernel<<<dim3(512), blk, 0, stream>>>(qkv, Vtg, maskb);

    // GEMM2 (64x128, 2-phase dbuf): out = attn @ Wot^T
    gemm2_bt<<<dim3(H_ / 128, M / 64), blk, 0, stream>>>(qkv, QKVW, Wot, out, H_, H_);
}

// Round 13
// 192.001 us; speedup vs baseline: 2.5841x; 1.0771x over previous
//
#include <hip/hip_runtime.h>
#include <math.h>

#define B_   2
#define S_   2048
#define H_   1024
#define NH_  16
#define NKV_ 4
#define HD_  64
#define R_   (NH_ / NKV_)   // 4 q-heads per kv-head
#define QKVW 1536           // qkv row width (q 0..1023 | k 1024..1279 | v 1280..1535)

typedef __attribute__((ext_vector_type(8))) short bf16x8;
typedef __attribute__((ext_vector_type(4))) float f32x4;

__device__ inline short f2bf(float f) {
    unsigned u = __float_as_uint(f);
    u += 0x7FFF + ((u >> 16) & 1);     // RNE to bf16
    return (short)(u >> 16);
}

__device__ inline float exp2fast(float x) {
#if __has_builtin(__builtin_amdgcn_exp2f)
    return __builtin_amdgcn_exp2f(x);
#else
    float r; asm volatile("v_exp_f32 %0, %1\n\ts_nop 1" : "=v"(r) : "v"(x)); return r;
#endif
}

__device__ inline unsigned cvt_pk_bf16(float lo, float hi) {
    unsigned r;
    asm("v_cvt_pk_bf16_f32 %0, %1, %2" : "=v"(r) : "v"(lo), "v"(hi));
    return r;
}

#define LOG2E 1.4426950408889634f

// async global->LDS, 16 B per lane (m97/m104 semantics).
__device__ inline void gload_lds16(const void* gptr, void* lptr) {
    __builtin_amdgcn_global_load_lds(
        (const __attribute__((address_space(1))) unsigned int*)gptr,
        (__attribute__((address_space(3))) unsigned int*)lptr,
        16, 0, 0);
}

// ---------------------------------------------------------------------------
// Weight transposes. 640 blocks of 64x64 tiles (R10/R12-proven).
// ---------------------------------------------------------------------------
__global__ __launch_bounds__(256) void tconv_all(const float* __restrict__ Wq,
                                                 const float* __restrict__ Wk,
                                                 const float* __restrict__ Wv,
                                                 const float* __restrict__ Wo,
                                                 short* __restrict__ Wqkvt,
                                                 short* __restrict__ Wot) {
    __shared__ short T[64][68];
    const int bx = blockIdx.x;
    const int tid = threadIdx.x;
    const float* W; short* Wt; int N, idx;
    if (bx < 256)      { W = Wq; Wt = Wqkvt;                     N = 1024; idx = bx; }
    else if (bx < 320) { W = Wk; Wt = Wqkvt + 1024 * 1024;       N = 256;  idx = bx - 256; }
    else if (bx < 384) { W = Wv; Wt = Wqkvt + 1280 * 1024;       N = 256;  idx = bx - 320; }
    else               { W = Wo; Wt = Wot;                       N = 1024; idx = bx - 384; }
    const int ntiles = N >> 6;
    const int n0 = (idx % ntiles) * 64;
    const int k0 = (idx / ntiles) * 64;

    const int r  = tid >> 4;
    const int c4 = (tid & 15) * 4;
#pragma unroll
    for (int t = 0; t < 4; t++) {
        int row = t * 16 + r;
        float4 v = *(const float4*)&W[(size_t)(k0 + row) * N + n0 + c4];
        T[c4 + 0][row] = f2bf(v.x);
        T[c4 + 1][row] = f2bf(v.y);
        T[c4 + 2][row] = f2bf(v.z);
        T[c4 + 3][row] = f2bf(v.w);
    }
    __syncthreads();
#pragma unroll
    for (int t = 0; t < 4; t++) {
        int row = t * 16 + r;          // n index
        short4 o = *(short4*)&T[row][c4];
        *(short4*)&Wt[(size_t)(n0 + row) * 1024 + k0 + c4] = o;
    }
}

// ---------------------------------------------------------------------------
// Fused GEMM1 (R10/R12-proven): qkv = bf16(x) @ Wqkvt^T, 64x128 tile, BK=32,
// 2-phase dbuf, fused fp32->bf16 A-convert. RoPE epilogue q/k; v scatter.
// ---------------------------------------------------------------------------
__global__ __launch_bounds__(256) void gemm1_fused(const float* __restrict__ x,
                                                   const short* __restrict__ Bt,
                                                   short* __restrict__ qkv,
                                                   short* __restrict__ Vtg,
                                                   const float* __restrict__ cosb,
                                                   const float* __restrict__ sinb) {
    __shared__ short Ah[2][64 * 32];    // 2 x 4 KB
    __shared__ short Bh[2][128 * 32];   // 2 x 8 KB

    const int tid  = threadIdx.x;
    const int w    = tid >> 6;
    const int lane = tid & 63;
    const int ln   = lane & 15;
    const int qd   = lane >> 4;
    const int wr   = w >> 1, wc = w & 1;
    const int row0 = blockIdx.y * 64;
    const int col0 = blockIdx.x * 128;

    const int sr = lane >> 2;        // 0..15 staging row-in-chunk
    const int sk = (lane & 3) * 8;   // k element offset
    const int ar  = tid >> 2;        // 0..63 A-convert row
    const int ac8 = (tid & 3) * 8;   // 0,8,16,24

    const float* xp  = x + (size_t)(row0 + ar) * 1024 + ac8;
    const short* bp0 = Bt + (size_t)(col0 + w * 32 + sr) * 1024 + sk;
    const short* bp1 = Bt + (size_t)(col0 + w * 32 + 16 + sr) * 1024 + sk;

    f32x4 acc[2][4];
#pragma unroll
    for (int mi = 0; mi < 2; mi++)
#pragma unroll
        for (int ni = 0; ni < 4; ni++)
            acc[mi][ni] = (f32x4){0.f, 0.f, 0.f, 0.f};

    // prologue: stage tile 0 into buf 0
    {
        float4 a1 = *(const float4*)xp;
        float4 a2 = *(const float4*)(xp + 4);
        bf16x8 o;
        o[0]=f2bf(a1.x); o[1]=f2bf(a1.y); o[2]=f2bf(a1.z); o[3]=f2bf(a1.w);
        o[4]=f2bf(a2.x); o[5]=f2bf(a2.y); o[6]=f2bf(a2.z); o[7]=f2bf(a2.w);
        *(bf16x8*)&Ah[0][ar * 32 + ac8] = o;
    }
    gload_lds16(bp0, &Bh[0][(w * 32) * 32]);
    gload_lds16(bp1, &Bh[0][(w * 32 + 16) * 32]);
    __syncthreads();

    for (int t = 0; t < 32; t++) {
        const int cur = t & 1, nxt = cur ^ 1;
        if (t + 1 < 32) {   // stage next tile first (overlaps MFMA below)
            const int k1 = (t + 1) * 32;
            gload_lds16(bp0 + k1, &Bh[nxt][(w * 32) * 32]);
            gload_lds16(bp1 + k1, &Bh[nxt][(w * 32 + 16) * 32]);
            float4 a1 = *(const float4*)(xp + k1);
            float4 a2 = *(const float4*)(xp + k1 + 4);
            bf16x8 o;
            o[0]=f2bf(a1.x); o[1]=f2bf(a1.y); o[2]=f2bf(a1.z); o[3]=f2bf(a1.w);
            o[4]=f2bf(a2.x); o[5]=f2bf(a2.y); o[6]=f2bf(a2.z); o[7]=f2bf(a2.w);
            *(bf16x8*)&Ah[nxt][ar * 32 + ac8] = o;
        }

        bf16x8 af[2], bfr[4];
#pragma unroll
        for (int mi = 0; mi < 2; mi++)
            af[mi] = *(const bf16x8*)&Ah[cur][(wr * 32 + mi * 16 + ln) * 32 + qd * 8];
#pragma unroll
        for (int ni = 0; ni < 4; ni++)
            bfr[ni] = *(const bf16x8*)&Bh[cur][(wc * 64 + ni * 16 + ln) * 32 + qd * 8];
#pragma unroll
        for (int mi = 0; mi < 2; mi++)
#pragma unroll
            for (int ni = 0; ni < 4; ni++)
                acc[mi][ni] = __builtin_amdgcn_mfma_f32_16x16x32_bf16(af[mi], bfr[ni], acc[mi][ni], 0, 0, 0);

        __syncthreads();   // drain lands after the MFMAs
    }

    const int colw = col0 + wc * 64;          // this wave's 64-col half
    if (colw < H_ + NKV_ * HD_) {
        // ---- q or k columns: RoPE in fp32, store bf16 to qkv ----
#pragma unroll
        for (int mi = 0; mi < 2; mi++)
#pragma unroll
            for (int i = 0; i < 4; i++) {
                const int row  = row0 + wr * 32 + mi * 16 + qd * 4 + i;
                const int spos = row & (S_ - 1);
                const float* cp = cosb + (size_t)spos * HD_;
                const float* sp = sinb + (size_t)spos * HD_;
                float o0[4];
#pragma unroll
                for (int ni = 0; ni < 2; ni++) {
                    const int d = ni * 16 + ln;
                    float x0 = acc[mi][ni][i], x1 = acc[mi][ni + 2][i];
                    o0[ni]     = x0 * cp[d]      - x1 * sp[d];
                    o0[ni + 2] = x1 * cp[d + 32] + x0 * sp[d + 32];
                }
                short* Cp = qkv + (size_t)row * QKVW + colw + ln;
#pragma unroll
                for (int ni = 0; ni < 4; ni++) Cp[ni * 16] = f2bf(o0[ni]);
            }
    } else {
        // ---- v columns: transposed scatter into Vtg[(b*NKV+g)*HD+d][s] ----
        const int g = (colw - (H_ + NKV_ * HD_)) >> 6;
#pragma unroll
        for (int mi = 0; mi < 2; mi++) {
            const int rbase = row0 + wr * 32 + mi * 16 + qd * 4;   // i = +0..3
            const int bg = ((rbase >> 11) * NKV_) + g;
            const int s0 = rbase & (S_ - 1);
#pragma unroll
            for (int ni = 0; ni < 4; ni++) {
                const int d = ni * 16 + ln;
                short4 pk = { f2bf(acc[mi][ni][0]), f2bf(acc[mi][ni][1]),
                              f2bf(acc[mi][ni][2]), f2bf(acc[mi][ni][3]) };
                *(short4*)&Vtg[((size_t)bg * HD_ + d) * S_ + s0] = pk;
            }
        }
    }
}

// ---------------------------------------------------------------------------
// bf16 MFMA GEMM (R9-proven), B^T form: C = A @ Bt^T, 64x128, 2-phase dbuf.
// ---------------------------------------------------------------------------
__global__ __launch_bounds__(256) void gemm2_bt(const short* __restrict__ A, int lda,
                                                const short* __restrict__ Bt,
                                                float* __restrict__ C, int ldc,
                                                int K) {
    __shared__ short Ah[2][64 * 32];
    __shared__ short Bh[2][128 * 32];

    const int tid  = threadIdx.x;
    const int w    = tid >> 6;
    const int lane = tid & 63;
    const int ln   = lane & 15;
    const int qd   = lane >> 4;
    const int wr   = w >> 1, wc = w & 1;
    const int row0 = blockIdx.y * 64;
    const int col0 = blockIdx.x * 128;

    const int sr = lane >> 2;
    const int sk = (lane & 3) * 8;

    const short* ap  = A + (size_t)(row0 + w * 16 + sr) * lda + sk;
    const short* bp0 = Bt + (size_t)(col0 + w * 32 + sr) * K + sk;
    const short* bp1 = Bt + (size_t)(col0 + w * 32 + 16 + sr) * K + sk;

    f32x4 acc[2][4];
#pragma unroll
    for (int mi = 0; mi < 2; mi++)
#pragma unroll
        for (int ni = 0; ni < 4; ni++)
            acc[mi][ni] = (f32x4){0.f, 0.f, 0.f, 0.f};

    const int nt = K >> 5;
    gload_lds16(ap,  &Ah[0][(w * 16) * 32]);
    gload_lds16(bp0, &Bh[0][(w * 32) * 32]);
    gload_lds16(bp1, &Bh[0][(w * 32 + 16) * 32]);
    __syncthreads();

    for (int t = 0; t < nt; t++) {
        const int cur = t & 1, nxt = cur ^ 1;
        if (t + 1 < nt) {
            const int k1 = (t + 1) * 32;
            gload_lds16(ap + k1,  &Ah[nxt][(w * 16) * 32]);
            gload_lds16(bp0 + k1, &Bh[nxt][(w * 32) * 32]);
            gload_lds16(bp1 + k1, &Bh[nxt][(w * 32 + 16) * 32]);
        }

        bf16x8 af[2], bfr[4];
#pragma unroll
        for (int mi = 0; mi < 2; mi++)
            af[mi] = *(const bf16x8*)&Ah[cur][(wr * 32 + mi * 16 + ln) * 32 + qd * 8];
#pragma unroll
        for (int ni = 0; ni < 4; ni++)
            bfr[ni] = *(const bf16x8*)&Bh[cur][(wc * 64 + ni * 16 + ln) * 32 + qd * 8];
#pragma unroll
        for (int mi = 0; mi < 2; mi++)
#pragma unroll
            for (int ni = 0; ni < 4; ni++)
                acc[mi][ni] = __builtin_amdgcn_mfma_f32_16x16x32_bf16(af[mi], bfr[ni], acc[mi][ni], 0, 0, 0);

        __syncthreads();
    }

#pragma unroll
    for (int mi = 0; mi < 2; mi++)
#pragma unroll
        for (int i = 0; i < 4; i++) {
            const size_t row = row0 + wr * 32 + mi * 16 + qd * 4 + i;
            float* Cp = C + row * ldc + col0 + wc * 64 + ln;
#pragma unroll
            for (int ni = 0; ni < 4; ni++) Cp[ni * 16] = acc[mi][ni][i];
        }
}

// ---------------------------------------------------------------------------
// bf16 MFMA flash attention v17 (BEST MEASURED: 57.5us @ R9, restored):
// uniform 34-step pair-blocks (the pair's two q-tiles run as SEQUENTIAL
// phases inside one 8-wave block -> every step has 8 dense waves) +
// log2-domain softmax + cvt_pk P-pack + pre-biased mask.
// v18 (KVBLK=128) and v19 (de-synced 2 blocks/CU) both regressed and were
// reverted: v19's makespan = max block length (heavy blocks ran alone at
// 4 waves/CU); v17's pair-in-one-block keeps 8 waves resident for all 34
// steps.
// ---------------------------------------------------------------------------
__global__ __launch_bounds__(512, 2) void attn_kernel(short* __restrict__ qkv,
                                                      const short* __restrict__ Vtg,
                                                      const float* __restrict__ maskb) {
    const int tid  = threadIdx.x;
    const int w    = tid >> 6;           // 0..7
    const int lane = tid & 63;
    const int ln   = lane & 15;
    const int qd   = lane >> 4;

    // fid&7 = bg -> XCD affinity for the K/V slice
    const int fid = blockIdx.x;          // 0..255
    const int bg  = fid & 7;             // b*NKV+g
    const int u   = fid >> 3;            // 0..31
    const int b   = bg >> 2;
    const int g   = bg & 3;
    const int h   = g * R_ + (u & 3);
    const int a   = u >> 2;              // pair index 0..7

    __shared__ short Ks[2][64 * 72];     // K  [key][dim], stride 72
    __shared__ short Vt[2][64 * 72];     // V^T [dim][key]
    __shared__ short Ps[8][16 * 72];     // per-wave P round-trip
    __shared__ float mskS[2][64];        // PRE-BIASED+SCALED: (1-m)*-1e9*log2e
    short* const ps = Ps[w];

    const short* const Kb = qkv + (size_t)b * S_ * QKVW + H_ + g * HD_;
    const short* const Vb = Vtg + (size_t)bg * HD_ * S_;
    const float* const mb = maskb + b * S_;

    const int fr = tid >> 3;             // 0..63 (staging row)
    const int fc = (tid & 7) * 8;        // staging col (elements)

#pragma unroll 1
    for (int ph = 0; ph < 2; ph++) {
        const int qt   = ph ? (15 - a) : a;
        const int rowb = qt * 128 + w * 16;   // this wave's 16-row strip
        const int ktd  = 2 * qt + (w >> 2);   // wave's diagonal tile
        const int ntp  = 2 * qt + 2;          // tiles this phase
        const int qrow = rowb + ln;

        // ---- Q B-frags: rows rowb+ln ----
        bf16x8 qf0, qf1;
        {
            const short* qp = qkv + (size_t)(b * S_ + rowb + ln) * QKVW + h * HD_;
            qf0 = *(const bf16x8*)&qp[qd * 8];
            qf1 = *(const bf16x8*)&qp[32 + qd * 8];
        }

        f32x4 O[4] = {};
        float mrow = -1e30f, lrow = 0.0f;    // mrow in log2 units

        // ---- stage tile 0 ----
        *(bf16x8*)&Ks[0][fr * 72 + fc] = *(const bf16x8*)&Kb[(size_t)fr * QKVW + fc];
        *(bf16x8*)&Vt[0][fr * 72 + fc] = *(const bf16x8*)&Vb[(size_t)fr * S_ + fc];
        if (tid < 64) mskS[0][tid] = (1.0f - mb[tid]) * (-1e9f * LOG2E);
        __syncthreads();

        int cur = 0;
#pragma unroll 1
        for (int kt = 0; kt < ntp; kt++) {
            const int base = kt * 64;
            const bool pf = (kt + 1 < ntp);

            // ---- prefetch tile kt+1 into registers (no wait) ----
            bf16x8 pk, pv;
            float pm = 0.0f;
            if (pf) {
                const int nb = base + 64;
                pk = *(const bf16x8*)&Kb[(size_t)(nb + fr) * QKVW + fc];
                pv = *(const bf16x8*)&Vb[(size_t)fr * S_ + nb + fc];
                if (tid < 64) pm = (1.0f - mb[nb + tid]) * (-1e9f * LOG2E);
            }

            if (kt <= ktd) {   // wave-uniform
                // ---- QK^T swapped: St[kg] = S^T[key][qrow=ln] ----
                f32x4 St[4];
#pragma unroll
                for (int kg = 0; kg < 4; kg++) {
                    bf16x8 ka0 = *(const bf16x8*)&Ks[cur][(kg * 16 + ln) * 72 + qd * 8];
                    bf16x8 ka1 = *(const bf16x8*)&Ks[cur][(kg * 16 + ln) * 72 + 32 + qd * 8];
                    f32x4 z = {0.f, 0.f, 0.f, 0.f};
                    z = __builtin_amdgcn_mfma_f32_16x16x32_bf16(ka0, qf0, z, 0, 0, 0);
                    St[kg] = __builtin_amdgcn_mfma_f32_16x16x32_bf16(ka1, qf1, z, 0, 0, 0);
                }

                // ---- V B-frags from LDS ----
                bf16x8 vb[2][4];
#pragma unroll
                for (int kc2 = 0; kc2 < 2; kc2++)
#pragma unroll
                    for (int dt = 0; dt < 4; dt++)
                        vb[kc2][dt] = *(const bf16x8*)&Vt[cur][(dt * 16 + ln) * 72 + kc2 * 32 + qd * 8];

                // ---- log2-domain scale + pre-scaled mask; causal on diag ----
                float sc[4][4];
#pragma unroll
                for (int kg = 0; kg < 4; kg++) {
                    float4 mv = *(const float4*)&mskS[cur][kg * 16 + qd * 4];
                    sc[kg][0] = fmaf(St[kg][0], 0.125f * LOG2E, mv.x);
                    sc[kg][1] = fmaf(St[kg][1], 0.125f * LOG2E, mv.y);
                    sc[kg][2] = fmaf(St[kg][2], 0.125f * LOG2E, mv.z);
                    sc[kg][3] = fmaf(St[kg][3], 0.125f * LOG2E, mv.w);
                }
                if (kt == ktd) {
#pragma unroll
                    for (int kg = 0; kg < 4; kg++) {
                        const int keyb = base + kg * 16 + qd * 4;
#pragma unroll
                        for (int i = 0; i < 4; i++)
                            if (keyb + i > qrow) sc[kg][i] = -1e30f;
                    }
                }

                float mx = sc[0][0];
#pragma unroll
                for (int kg = 0; kg < 4; kg++)
#pragma unroll
                    for (int i = 0; i < 4; i++) mx = fmaxf(mx, sc[kg][i]);
                mx = fmaxf(mx, __shfl_xor(mx, 16));
                mx = fmaxf(mx, __shfl_xor(mx, 32));

                // defer-max (T13): 8 ln-units = 11.5416 log2-units
                if (__ballot(mx > mrow + 11.5416f)) {
                    float nm    = fmaxf(mrow, mx);
                    float alpha = exp2fast(mrow - nm);
                    lrow *= alpha;
#pragma unroll
                    for (int i = 0; i < 4; i++) {
                        float av = __shfl(alpha, qd * 4 + i);
#pragma unroll
                        for (int dt = 0; dt < 4; dt++) O[dt][i] *= av;
                    }
                    mrow = nm;
                }
                const float nm = mrow;

                float ls = 0.0f;
#pragma unroll
                for (int kg = 0; kg < 4; kg++)
#pragma unroll
                    for (int i = 0; i < 4; i++) {
                        float p = exp2fast(sc[kg][i] - nm);
                        sc[kg][i] = p;
                        ls += p;
                    }
                ls += __shfl_xor(ls, 16);
                ls += __shfl_xor(ls, 32);
                lrow += ls;

                // ---- P pack via cvt_pk (2 f32 -> 1 u32 of 2 bf16) ----
#pragma unroll
                for (int kg = 0; kg < 4; kg++) {
                    uint2 pw;
                    pw.x = cvt_pk_bf16(sc[kg][0], sc[kg][1]);
                    pw.y = cvt_pk_bf16(sc[kg][2], sc[kg][3]);
                    *(uint2*)&ps[ln * 72 + kg * 16 + qd * 4] = pw;
                }

                // ---- PV: O += P @ V (same-wave LDS write->read) ----
#pragma unroll
                for (int kc2 = 0; kc2 < 2; kc2++) {
                    bf16x8 pa = *(const bf16x8*)&ps[ln * 72 + kc2 * 32 + qd * 8];
#pragma unroll
                    for (int dt = 0; dt < 4; dt++)
                        O[dt] = __builtin_amdgcn_mfma_f32_16x16x32_bf16(pa, vb[kc2][dt], O[dt], 0, 0, 0);
                }
            }

            // ---- write prefetched tile into the other buffer ----
            if (pf) {
                const int nxt = cur ^ 1;
                *(bf16x8*)&Ks[nxt][fr * 72 + fc] = pk;
                *(bf16x8*)&Vt[nxt][fr * 72 + fc] = pv;
                if (tid < 64) mskS[nxt][tid] = pm;
            }
            __syncthreads();
            cur ^= 1;
        }

        // ---- finalize this phase: write bf16 into q-slice ----
#pragma unroll
        for (int i = 0; i < 4; i++) {
            float li  = __shfl(lrow, qd * 4 + i);
            float inv = 1.0f / li;
            const int row = rowb + qd * 4 + i;
            short* op = qkv + (size_t)(b * S_ + row) * QKVW + h * HD_ + ln;
#pragma unroll
            for (int dt = 0; dt < 4; dt++) op[dt * 16] = f2bf(O[dt][i] * inv);
        }
    }
}

// ---------------------------------------------------------------------------
extern "C" void kernel_launch(void* const* d_in, const int* in_sizes, int n_in,
                              void* d_out, int out_size, void* d_ws, size_t ws_size,
                              hipStream_t stream) {
    const float* x     = (const float*)d_in[0];
    const float* cosb  = (const float*)d_in[1];
    const float* sinb  = (const float*)d_in[2];
    const float* maskb = (const float*)d_in[3];
    const float* Wq    = (const float*)d_in[4];
    const float* Wk    = (const float*)d_in[5];
    const float* Wv    = (const float*)d_in[6];
    const float* Wo    = (const float*)d_in[7];

    const int M = B_ * S_;   // 4096

    // ws: qkv | Wqkvt | Wot | Vtg  (19.9 MB bf16). d_out only for out.
    short* qkv   = (short*)d_ws;                     // [4096][1536]
    short* Wqkvt = qkv + (size_t)M * QKVW;           // [1536][1024]
    short* Wot   = Wqkvt + (size_t)QKVW * H_;        // [1024][1024]
    short* Vtg   = Wot + (size_t)H_ * H_;            // [8*64][2048]
    float* out   = (float*)d_out;

    dim3 blk(256);

    // weight transposes
    tconv_all<<<dim3(640), blk, 0, stream>>>(Wq, Wk, Wv, Wo, Wqkvt, Wot);

    // GEMM1 fused (64x128, 2-phase dbuf, fused A-convert)
    gemm1_fused<<<dim3(QKVW / 128, M / 64), blk, 0, stream>>>(x, Wqkvt, qkv, Vtg, cosb, sinb);

    // attention: 256 pair-blocks x 512 threads, uniform 34 steps/block
    attn_kernel<<<dim3(256), dim3(512), 0, stream>>>(qkv, Vtg, maskb);

    // GEMM2 (64x128, 2-phase dbuf): out = attn @ Wot^T
    gemm2_bt<<<dim3(H_ / 128, M / 64), blk, 0, stream>>>(qkv, QKVW, Wot, out, H_, H_);
}

// Round 15
// 187.241 us; speedup vs baseline: 2.6498x; 1.0254x over previous
//
#include <hip/hip_runtime.h>
#include <math.h>

#define B_   2
#define S_   2048
#define H_   1024
#define NH_  16
#define NKV_ 4
#define HD_  64
#define R_   (NH_ / NKV_)   // 4 q-heads per kv-head
#define QKVW 1536           // qkv row width (q 0..1023 | k 1024..1279 | v 1280..1535)

typedef __attribute__((ext_vector_type(8))) short bf16x8;
typedef __attribute__((ext_vector_type(4))) float f32x4;

__device__ inline short f2bf(float f) {
    unsigned u = __float_as_uint(f);
    u += 0x7FFF + ((u >> 16) & 1);     // RNE to bf16
    return (short)(u >> 16);
}

__device__ inline float exp2fast(float x) {
#if __has_builtin(__builtin_amdgcn_exp2f)
    return __builtin_amdgcn_exp2f(x);
#else
    float r; asm volatile("v_exp_f32 %0, %1\n\ts_nop 1" : "=v"(r) : "v"(x)); return r;
#endif
}

__device__ inline unsigned cvt_pk_bf16(float lo, float hi) {
    unsigned r;
    asm("v_cvt_pk_bf16_f32 %0, %1, %2" : "=v"(r) : "v"(lo), "v"(hi));
    return r;
}

#define LOG2E 1.4426950408889634f

// async global->LDS, 16 B per lane (m97/m104 semantics).
__device__ inline void gload_lds16(const void* gptr, void* lptr) {
    __builtin_amdgcn_global_load_lds(
        (const __attribute__((address_space(1))) unsigned int*)gptr,
        (__attribute__((address_space(3))) unsigned int*)lptr,
        16, 0, 0);
}

// ---------------------------------------------------------------------------
// Weight transposes. 640 blocks of 64x64 tiles (R10/R12/R13-proven).
// ---------------------------------------------------------------------------
__global__ __launch_bounds__(256) void tconv_all(const float* __restrict__ Wq,
                                                 const float* __restrict__ Wk,
                                                 const float* __restrict__ Wv,
                                                 const float* __restrict__ Wo,
                                                 short* __restrict__ Wqkvt,
                                                 short* __restrict__ Wot) {
    __shared__ short T[64][68];
    const int bx = blockIdx.x;
    const int tid = threadIdx.x;
    const float* W; short* Wt; int N, idx;
    if (bx < 256)      { W = Wq; Wt = Wqkvt;                     N = 1024; idx = bx; }
    else if (bx < 320) { W = Wk; Wt = Wqkvt + 1024 * 1024;       N = 256;  idx = bx - 256; }
    else if (bx < 384) { W = Wv; Wt = Wqkvt + 1280 * 1024;       N = 256;  idx = bx - 320; }
    else               { W = Wo; Wt = Wot;                       N = 1024; idx = bx - 384; }
    const int ntiles = N >> 6;
    const int n0 = (idx % ntiles) * 64;
    const int k0 = (idx / ntiles) * 64;

    const int r  = tid >> 4;
    const int c4 = (tid & 15) * 4;
#pragma unroll
    for (int t = 0; t < 4; t++) {
        int row = t * 16 + r;
        float4 v = *(const float4*)&W[(size_t)(k0 + row) * N + n0 + c4];
        T[c4 + 0][row] = f2bf(v.x);
        T[c4 + 1][row] = f2bf(v.y);
        T[c4 + 2][row] = f2bf(v.z);
        T[c4 + 3][row] = f2bf(v.w);
    }
    __syncthreads();
#pragma unroll
    for (int t = 0; t < 4; t++) {
        int row = t * 16 + r;          // n index
        short4 o = *(short4*)&T[row][c4];
        *(short4*)&Wt[(size_t)(n0 + row) * 1024 + k0 + c4] = o;
    }
}

// ---------------------------------------------------------------------------
// Fused GEMM1: qkv = bf16(x) @ Wqkvt^T, 64x128 tile, BK=32, 2-phase dbuf,
// fused fp32->bf16 A-convert (R10/R13-proven internals).
// GRID TRANSPOSED for L2 panel locality: blockIdx.x = row-chunk (fastest,
// 64), blockIdx.y = col-panel (12) -> 64 consecutively-dispatched blocks
// share ONE 256 KB weight panel; ~8 land per XCD and reuse it from L2
// (old x=col order cycled all 12 panels -> per-XCD L2 thrash of 24 MB).
// ---------------------------------------------------------------------------
__global__ __launch_bounds__(256) void gemm1_fused(const float* __restrict__ x,
                                                   const short* __restrict__ Bt,
                                                   short* __restrict__ qkv,
                                                   short* __restrict__ Vtg,
                                                   const float* __restrict__ cosb,
                                                   const float* __restrict__ sinb) {
    __shared__ short Ah[2][64 * 32];    // 2 x 4 KB
    __shared__ short Bh[2][128 * 32];   // 2 x 8 KB

    const int tid  = threadIdx.x;
    const int w    = tid >> 6;
    const int lane = tid & 63;
    const int ln   = lane & 15;
    const int qd   = lane >> 4;
    const int wr   = w >> 1, wc = w & 1;
    const int row0 = blockIdx.x * 64;    // TRANSPOSED: x = row-chunk
    const int col0 = blockIdx.y * 128;   //             y = col-panel

    const int sr = lane >> 2;        // 0..15 staging row-in-chunk
    const int sk = (lane & 3) * 8;   // k element offset
    const int ar  = tid >> 2;        // 0..63 A-convert row
    const int ac8 = (tid & 3) * 8;   // 0,8,16,24

    const float* xp  = x + (size_t)(row0 + ar) * 1024 + ac8;
    const short* bp0 = Bt + (size_t)(col0 + w * 32 + sr) * 1024 + sk;
    const short* bp1 = Bt + (size_t)(col0 + w * 32 + 16 + sr) * 1024 + sk;

    f32x4 acc[2][4];
#pragma unroll
    for (int mi = 0; mi < 2; mi++)
#pragma unroll
        for (int ni = 0; ni < 4; ni++)
            acc[mi][ni] = (f32x4){0.f, 0.f, 0.f, 0.f};

    // prologue: stage tile 0 into buf 0
    {
        float4 a1 = *(const float4*)xp;
        float4 a2 = *(const float4*)(xp + 4);
        bf16x8 o;
        o[0]=f2bf(a1.x); o[1]=f2bf(a1.y); o[2]=f2bf(a1.z); o[3]=f2bf(a1.w);
        o[4]=f2bf(a2.x); o[5]=f2bf(a2.y); o[6]=f2bf(a2.z); o[7]=f2bf(a2.w);
        *(bf16x8*)&Ah[0][ar * 32 + ac8] = o;
    }
    gload_lds16(bp0, &Bh[0][(w * 32) * 32]);
    gload_lds16(bp1, &Bh[0][(w * 32 + 16) * 32]);
    __syncthreads();

    for (int t = 0; t < 32; t++) {
        const int cur = t & 1, nxt = cur ^ 1;
        if (t + 1 < 32) {   // stage next tile first (overlaps MFMA below)
            const int k1 = (t + 1) * 32;
            gload_lds16(bp0 + k1, &Bh[nxt][(w * 32) * 32]);
            gload_lds16(bp1 + k1, &Bh[nxt][(w * 32 + 16) * 32]);
            float4 a1 = *(const float4*)(xp + k1);
            float4 a2 = *(const float4*)(xp + k1 + 4);
            bf16x8 o;
            o[0]=f2bf(a1.x); o[1]=f2bf(a1.y); o[2]=f2bf(a1.z); o[3]=f2bf(a1.w);
            o[4]=f2bf(a2.x); o[5]=f2bf(a2.y); o[6]=f2bf(a2.z); o[7]=f2bf(a2.w);
            *(bf16x8*)&Ah[nxt][ar * 32 + ac8] = o;
        }

        bf16x8 af[2], bfr[4];
#pragma unroll
        for (int mi = 0; mi < 2; mi++)
            af[mi] = *(const bf16x8*)&Ah[cur][(wr * 32 + mi * 16 + ln) * 32 + qd * 8];
#pragma unroll
        for (int ni = 0; ni < 4; ni++)
            bfr[ni] = *(const bf16x8*)&Bh[cur][(wc * 64 + ni * 16 + ln) * 32 + qd * 8];
#pragma unroll
        for (int mi = 0; mi < 2; mi++)
#pragma unroll
            for (int ni = 0; ni < 4; ni++)
                acc[mi][ni] = __builtin_amdgcn_mfma_f32_16x16x32_bf16(af[mi], bfr[ni], acc[mi][ni], 0, 0, 0);

        __syncthreads();   // drain lands after the MFMAs
    }

    const int colw = col0 + wc * 64;          // this wave's 64-col half
    if (colw < H_ + NKV_ * HD_) {
        // ---- q or k columns: RoPE in fp32, store bf16 to qkv ----
#pragma unroll
        for (int mi = 0; mi < 2; mi++)
#pragma unroll
            for (int i = 0; i < 4; i++) {
                const int row  = row0 + wr * 32 + mi * 16 + qd * 4 + i;
                const int spos = row & (S_ - 1);
                const float* cp = cosb + (size_t)spos * HD_;
                const float* sp = sinb + (size_t)spos * HD_;
                float o0[4];
#pragma unroll
                for (int ni = 0; ni < 2; ni++) {
                    const int d = ni * 16 + ln;
                    float x0 = acc[mi][ni][i], x1 = acc[mi][ni + 2][i];
                    o0[ni]     = x0 * cp[d]      - x1 * sp[d];
                    o0[ni + 2] = x1 * cp[d + 32] + x0 * sp[d + 32];
                }
                short* Cp = qkv + (size_t)row * QKVW + colw + ln;
#pragma unroll
                for (int ni = 0; ni < 4; ni++) Cp[ni * 16] = f2bf(o0[ni]);
            }
    } else {
        // ---- v columns: transposed scatter into Vtg[(b*NKV+g)*HD+d][s] ----
        const int g = (colw - (H_ + NKV_ * HD_)) >> 6;
#pragma unroll
        for (int mi = 0; mi < 2; mi++) {
            const int rbase = row0 + wr * 32 + mi * 16 + qd * 4;   // i = +0..3
            const int bg = ((rbase >> 11) * NKV_) + g;
            const int s0 = rbase & (S_ - 1);
#pragma unroll
            for (int ni = 0; ni < 4; ni++) {
                const int d = ni * 16 + ln;
                short4 pk = { f2bf(acc[mi][ni][0]), f2bf(acc[mi][ni][1]),
                              f2bf(acc[mi][ni][2]), f2bf(acc[mi][ni][3]) };
                *(short4*)&Vtg[((size_t)bg * HD_ + d) * S_ + s0] = pk;
            }
        }
    }
}

// ---------------------------------------------------------------------------
// bf16 MFMA GEMM, B^T form: C = A @ Bt^T, 64x128, 2-phase dbuf
// (R9/R13-proven internals). Grid transposed like gemm1: x = row-chunk
// (64 fastest), y = col-panel (8) -> weight-panel L2 reuse.
// ---------------------------------------------------------------------------
__global__ __launch_bounds__(256) void gemm2_bt(const short* __restrict__ A, int lda,
                                                const short* __restrict__ Bt,
                                                float* __restrict__ C, int ldc,
                                                int K) {
    __shared__ short Ah[2][64 * 32];
    __shared__ short Bh[2][128 * 32];

    const int tid  = threadIdx.x;
    const int w    = tid >> 6;
    const int lane = tid & 63;
    const int ln   = lane & 15;
    const int qd   = lane >> 4;
    const int wr   = w >> 1, wc = w & 1;
    const int row0 = blockIdx.x * 64;    // TRANSPOSED: x = row-chunk
    const int col0 = blockIdx.y * 128;   //             y = col-panel

    const int sr = lane >> 2;
    const int sk = (lane & 3) * 8;

    const short* ap  = A + (size_t)(row0 + w * 16 + sr) * lda + sk;
    const short* bp0 = Bt + (size_t)(col0 + w * 32 + sr) * K + sk;
    const short* bp1 = Bt + (size_t)(col0 + w * 32 + 16 + sr) * K + sk;

    f32x4 acc[2][4];
#pragma unroll
    for (int mi = 0; mi < 2; mi++)
#pragma unroll
        for (int ni = 0; ni < 4; ni++)
            acc[mi][ni] = (f32x4){0.f, 0.f, 0.f, 0.f};

    const int nt = K >> 5;
    gload_lds16(ap,  &Ah[0][(w * 16) * 32]);
    gload_lds16(bp0, &Bh[0][(w * 32) * 32]);
    gload_lds16(bp1, &Bh[0][(w * 32 + 16) * 32]);
    __syncthreads();

    for (int t = 0; t < nt; t++) {
        const int cur = t & 1, nxt = cur ^ 1;
        if (t + 1 < nt) {
            const int k1 = (t + 1) * 32;
            gload_lds16(ap + k1,  &Ah[nxt][(w * 16) * 32]);
            gload_lds16(bp0 + k1, &Bh[nxt][(w * 32) * 32]);
            gload_lds16(bp1 + k1, &Bh[nxt][(w * 32 + 16) * 32]);
        }

        bf16x8 af[2], bfr[4];
#pragma unroll
        for (int mi = 0; mi < 2; mi++)
            af[mi] = *(const bf16x8*)&Ah[cur][(wr * 32 + mi * 16 + ln) * 32 + qd * 8];
#pragma unroll
        for (int ni = 0; ni < 4; ni++)
            bfr[ni] = *(const bf16x8*)&Bh[cur][(wc * 64 + ni * 16 + ln) * 32 + qd * 8];
#pragma unroll
        for (int mi = 0; mi < 2; mi++)
#pragma unroll
            for (int ni = 0; ni < 4; ni++)
                acc[mi][ni] = __builtin_amdgcn_mfma_f32_16x16x32_bf16(af[mi], bfr[ni], acc[mi][ni], 0, 0, 0);

        __syncthreads();
    }

#pragma unroll
    for (int mi = 0; mi < 2; mi++)
#pragma unroll
        for (int i = 0; i < 4; i++) {
            const size_t row = row0 + wr * 32 + mi * 16 + qd * 4 + i;
            float* Cp = C + row * ldc + col0 + wc * 64 + ln;
#pragma unroll
            for (int ni = 0; ni < 4; ni++) Cp[ni * 16] = acc[mi][ni][i];
        }
}

// ---------------------------------------------------------------------------
// bf16 MFMA flash attention v17 (REVERTED, passed R9/R13 at 57.0-57.5us):
// uniform 34-step pair-blocks + log2-domain softmax + cvt_pk P-pack +
// pre-biased mask. v20's T15 pipeline FAILED correctness (absmax 6e30,
// root cause not identified after full dataflow audit) -> reverted per
// rigor discipline; T15 marked not-transferable to this structure.
// ---------------------------------------------------------------------------
__global__ __launch_bounds__(512, 2) void attn_kernel(short* __restrict__ qkv,
                                                      const short* __restrict__ Vtg,
                                                      const float* __restrict__ maskb) {
    const int tid  = threadIdx.x;
    const int w    = tid >> 6;           // 0..7
    const int lane = tid & 63;
    const int ln   = lane & 15;
    const int qd   = lane >> 4;

    // fid&7 = bg -> XCD affinity for the K/V slice
    const int fid = blockIdx.x;          // 0..255
    const int bg  = fid & 7;             // b*NKV+g
    const int u   = fid >> 3;            // 0..31
    const int b   = bg >> 2;
    const int g   = bg & 3;
    const int h   = g * R_ + (u & 3);
    const int a   = u >> 2;              // pair index 0..7

    __shared__ short Ks[2][64 * 72];     // K  [key][dim], stride 72
    __shared__ short Vt[2][64 * 72];     // V^T [dim][key]
    __shared__ short Ps[8][16 * 72];     // per-wave P round-trip
    __shared__ float mskS[2][64];        // PRE-BIASED+SCALED: (1-m)*-1e9*log2e
    short* const ps = Ps[w];

    const short* const Kb = qkv + (size_t)b * S_ * QKVW + H_ + g * HD_;
    const short* const Vb = Vtg + (size_t)bg * HD_ * S_;
    const float* const mb = maskb + b * S_;

    const int fr = tid >> 3;             // 0..63 (staging row)
    const int fc = (tid & 7) * 8;        // staging col (elements)

#pragma unroll 1
    for (int ph = 0; ph < 2; ph++) {
        const int qt   = ph ? (15 - a) : a;
        const int rowb = qt * 128 + w * 16;   // this wave's 16-row strip
        const int ktd  = 2 * qt + (w >> 2);   // wave's diagonal tile
        const int ntp  = 2 * qt + 2;          // tiles this phase
        const int qrow = rowb + ln;

        // ---- Q B-frags: rows rowb+ln ----
        bf16x8 qf0, qf1;
        {
            const short* qp = qkv + (size_t)(b * S_ + rowb + ln) * QKVW + h * HD_;
            qf0 = *(const bf16x8*)&qp[qd * 8];
            qf1 = *(const bf16x8*)&qp[32 + qd * 8];
        }

        f32x4 O[4] = {};
        float mrow = -1e30f, lrow = 0.0f;    // mrow in log2 units

        // ---- stage tile 0 ----
        *(bf16x8*)&Ks[0][fr * 72 + fc] = *(const bf16x8*)&Kb[(size_t)fr * QKVW + fc];
        *(bf16x8*)&Vt[0][fr * 72 + fc] = *(const bf16x8*)&Vb[(size_t)fr * S_ + fc];
        if (tid < 64) mskS[0][tid] = (1.0f - mb[tid]) * (-1e9f * LOG2E);
        __syncthreads();

        int cur = 0;
#pragma unroll 1
        for (int kt = 0; kt < ntp; kt++) {
            const int base = kt * 64;
            const bool pf = (kt + 1 < ntp);

            // ---- prefetch tile kt+1 into registers (no wait) ----
            bf16x8 pk, pv;
            float pm = 0.0f;
            if (pf) {
                const int nb = base + 64;
                pk = *(const bf16x8*)&Kb[(size_t)(nb + fr) * QKVW + fc];
                pv = *(const bf16x8*)&Vb[(size_t)fr * S_ + nb + fc];
                if (tid < 64) pm = (1.0f - mb[nb + tid]) * (-1e9f * LOG2E);
            }

            if (kt <= ktd) {   // wave-uniform
                // ---- QK^T swapped: St[kg] = S^T[key][qrow=ln] ----
                f32x4 St[4];
#pragma unroll
                for (int kg = 0; kg < 4; kg++) {
                    bf16x8 ka0 = *(const bf16x8*)&Ks[cur][(kg * 16 + ln) * 72 + qd * 8];
                    bf16x8 ka1 = *(const bf16x8*)&Ks[cur][(kg * 16 + ln) * 72 + 32 + qd * 8];
                    f32x4 z = {0.f, 0.f, 0.f, 0.f};
                    z = __builtin_amdgcn_mfma_f32_16x16x32_bf16(ka0, qf0, z, 0, 0, 0);
                    St[kg] = __builtin_amdgcn_mfma_f32_16x16x32_bf16(ka1, qf1, z, 0, 0, 0);
                }

                // ---- V B-frags from LDS ----
                bf16x8 vb[2][4];
#pragma unroll
                for (int kc2 = 0; kc2 < 2; kc2++)
#pragma unroll
                    for (int dt = 0; dt < 4; dt++)
                        vb[kc2][dt] = *(const bf16x8*)&Vt[cur][(dt * 16 + ln) * 72 + kc2 * 32 + qd * 8];

                // ---- log2-domain scale + pre-scaled mask; causal on diag ----
                float sc[4][4];
#pragma unroll
                for (int kg = 0; kg < 4; kg++) {
                    float4 mv = *(const float4*)&mskS[cur][kg * 16 + qd * 4];
                    sc[kg][0] = fmaf(St[kg][0], 0.125f * LOG2E, mv.x);
                    sc[kg][1] = fmaf(St[kg][1], 0.125f * LOG2E, mv.y);
                    sc[kg][2] = fmaf(St[kg][2], 0.125f * LOG2E, mv.z);
                    sc[kg][3] = fmaf(St[kg][3], 0.125f * LOG2E, mv.w);
                }
                if (kt == ktd) {
#pragma unroll
                    for (int kg = 0; kg < 4; kg++) {
                        const int keyb = base + kg * 16 + qd * 4;
#pragma unroll
                        for (int i = 0; i < 4; i++)
                            if (keyb + i > qrow) sc[kg][i] = -1e30f;
                    }
                }

                float mx = sc[0][0];
#pragma unroll
                for (int kg = 0; kg < 4; kg++)
#pragma unroll
                    for (int i = 0; i < 4; i++) mx = fmaxf(mx, sc[kg][i]);
                mx = fmaxf(mx, __shfl_xor(mx, 16));
                mx = fmaxf(mx, __shfl_xor(mx, 32));

                // defer-max (T13): 8 ln-units = 11.5416 log2-units
                if (__ballot(mx > mrow + 11.5416f)) {
                    float nm    = fmaxf(mrow, mx);
                    float alpha = exp2fast(mrow - nm);
                    lrow *= alpha;
#pragma unroll
                    for (int i = 0; i < 4; i++) {
                        float av = __shfl(alpha, qd * 4 + i);
#pragma unroll
                        for (int dt = 0; dt < 4; dt++) O[dt][i] *= av;
                    }
                    mrow = nm;
                }
                const float nm = mrow;

                float ls = 0.0f;
#pragma unroll
                for (int kg = 0; kg < 4; kg++)
#pragma unroll
                    for (int i = 0; i < 4; i++) {
                        float p = exp2fast(sc[kg][i] - nm);
                        sc[kg][i] = p;
                        ls += p;
                    }
                ls += __shfl_xor(ls, 16);
                ls += __shfl_xor(ls, 32);
                lrow += ls;

                // ---- P pack via cvt_pk (2 f32 -> 1 u32 of 2 bf16) ----
#pragma unroll
                for (int kg = 0; kg < 4; kg++) {
                    uint2 pw;
                    pw.x = cvt_pk_bf16(sc[kg][0], sc[kg][1]);
                    pw.y = cvt_pk_bf16(sc[kg][2], sc[kg][3]);
                    *(uint2*)&ps[ln * 72 + kg * 16 + qd * 4] = pw;
                }

                // ---- PV: O += P @ V (same-wave LDS write->read) ----
#pragma unroll
                for (int kc2 = 0; kc2 < 2; kc2++) {
                    bf16x8 pa = *(const bf16x8*)&ps[ln * 72 + kc2 * 32 + qd * 8];
#pragma unroll
                    for (int dt = 0; dt < 4; dt++)
                        O[dt] = __builtin_amdgcn_mfma_f32_16x16x32_bf16(pa, vb[kc2][dt], O[dt], 0, 0, 0);
                }
            }

            // ---- write prefetched tile into the other buffer ----
            if (pf) {
                const int nxt = cur ^ 1;
                *(bf16x8*)&Ks[nxt][fr * 72 + fc] = pk;
                *(bf16x8*)&Vt[nxt][fr * 72 + fc] = pv;
                if (tid < 64) mskS[nxt][tid] = pm;
            }
            __syncthreads();
            cur ^= 1;
        }

        // ---- finalize this phase: write bf16 into q-slice ----
#pragma unroll
        for (int i = 0; i < 4; i++) {
            float li  = __shfl(lrow, qd * 4 + i);
            float inv = 1.0f / li;
            const int row = rowb + qd * 4 + i;
            short* op = qkv + (size_t)(b * S_ + row) * QKVW + h * HD_ + ln;
#pragma unroll
            for (int dt = 0; dt < 4; dt++) op[dt * 16] = f2bf(O[dt][i] * inv);
        }
    }
}

// ---------------------------------------------------------------------------
extern "C" void kernel_launch(void* const* d_in, const int* in_sizes, int n_in,
                              void* d_out, int out_size, void* d_ws, size_t ws_size,
                              hipStream_t stream) {
    const float* x     = (const float*)d_in[0];
    const float* cosb  = (const float*)d_in[1];
    const float* sinb  = (const float*)d_in[2];
    const float* maskb = (const float*)d_in[3];
    const float* Wq    = (const float*)d_in[4];
    const float* Wk    = (const float*)d_in[5];
    const float* Wv    = (const float*)d_in[6];
    const float* Wo    = (const float*)d_in[7];

    const int M = B_ * S_;   // 4096

    // ws: qkv | Wqkvt | Wot | Vtg  (19.9 MB bf16). d_out only for out.
    short* qkv   = (short*)d_ws;                     // [4096][1536]
    short* Wqkvt = qkv + (size_t)M * QKVW;           // [1536][1024]
    short* Wot   = Wqkvt + (size_t)QKVW * H_;        // [1024][1024]
    short* Vtg   = Wot + (size_t)H_ * H_;            // [8*64][2048]
    float* out   = (float*)d_out;

    dim3 blk(256);

    // weight transposes
    tconv_all<<<dim3(640), blk, 0, stream>>>(Wq, Wk, Wv, Wo, Wqkvt, Wot);

    // GEMM1 fused (64x128, 2-phase dbuf, fused A-convert); grid transposed:
    // x = row-chunk (64 fastest, shares weight panel), y = col-panel (12)
    gemm1_fused<<<dim3(M / 64, QKVW / 128), blk, 0, stream>>>(x, Wqkvt, qkv, Vtg, cosb, sinb);

    // attention: 256 pair-blocks x 512 threads, uniform 34 steps/block
    attn_kernel<<<dim3(256), dim3(512), 0, stream>>>(qkv, Vtg, maskb);

    // GEMM2 (64x128, 2-phase dbuf); grid transposed likewise (64 x 8)
    gemm2_bt<<<dim3(M / 64, H_ / 128), blk, 0, stream>>>(qkv, QKVW, Wot, out, H_, H_);
}